// Round 3
// baseline (3237.769 us; speedup 1.0000x reference)
//
#include <hip/hip_runtime.h>
#include <hip/hip_bf16.h>

#define DI __device__ __forceinline__

typedef short bf16x8 __attribute__((ext_vector_type(8)));
typedef float f32x4 __attribute__((ext_vector_type(4)));
typedef int   i32x4 __attribute__((ext_vector_type(4)));
typedef unsigned short u16;

constexpr int TT = 512, BB = 256, HH = 256, VV = 128;
constexpr int TC = 64, NCH = TT / TC;   // chunk of timesteps per rec launch

DI u16 f2b(float f){ __hip_bfloat16 h = __float2bfloat16(f); u16 r; __builtin_memcpy(&r,&h,2); return r; }
DI float fsig(float x){ return __builtin_amdgcn_rcpf(1.0f + __builtin_amdgcn_exp2f(-1.4426950408889634f*x)); }
DI float ftanh(float x){ return 1.0f - 2.0f*__builtin_amdgcn_rcpf(1.0f + __builtin_amdgcn_exp2f(2.8853900817779268f*x)); }
DI f32x4 mfma16(bf16x8 a, bf16x8 b, f32x4 c){ return __builtin_amdgcn_mfma_f32_16x16x32_bf16(a,b,c,0,0,0); }

// ---------------------------------------------------------------------------
// pack W [N][K] f32 -> B-fragment layout: frag(ntg,kt,lane)[j] =
//   bf16( W[ntg*16 + (lane&15)][kt*32 + (lane>>4)*8 + j] ), linear at tid*8.
// ---------------------------------------------------------------------------
__global__ void pack_b(const float* __restrict__ W, u16* __restrict__ o, int N, int K){
  const int tid = blockIdx.x*256 + threadIdx.x;
  const int KT = K >> 5;
  const int total = (N>>4)*KT*64;
  if (tid >= total) return;
  const int lane = tid & 63;
  const int rest = tid >> 6;
  const int kt  = rest % KT;
  const int ntg = rest / KT;
  const int n  = (ntg<<4) + (lane&15);
  const int k0 = (kt<<5) + ((lane>>4)<<3);
  const float* s = W + (size_t)n*K + k0;
  bf16x8 pv;
#pragma unroll
  for (int j=0;j<8;++j) pv[j] = (short)f2b(s[j]);
  *(bf16x8*)(o + (size_t)tid*8) = pv;
}

__global__ void bias_sum(const float* a0,const float* b0,float* o0,
                         const float* a1,const float* b1,float* o1){
  int i = blockIdx.x*256 + threadIdx.x;
  if (i < 1024) o0[i] = a0[i] + b0[i];
  else if (i < 2048) { int j=i-1024; o1[j] = a1[j] + b1[j]; }
}

// ---------------------------------------------------------------------------
// MFMA GEMM: C[M x N] = A[M x K] * Bpacked^T + bias.  512 thr = 8 waves
// (4 M-waves x 2 N-waves), block tile 64 x (NT*32). Static LDS for B stage.
// __syncthreads() before epilogue: REQUIRED for the in-place FC (C aliases A
// rows within the block) — all A-loads must drain before any C-store.
// ---------------------------------------------------------------------------
template<int KT, int NT, bool AF32, bool CB16>
__global__ __launch_bounds__(512,2) void gemm_xg(const void* __restrict__ A_,
    const u16* __restrict__ Bp, const float* __restrict__ bias,
    void* __restrict__ C_, int lda, int ldc)
{
  __shared__ char smem[2*NT*KT*64*16];
  const int tid = threadIdx.x;
  const int l = tid & 63, w = tid >> 6;
  const int l15 = l & 15, g4 = l >> 4;
  const int mw = w >> 1, nw = w & 1;
  const int col0 = blockIdx.x * (NT*32);
  const int row0 = blockIdx.y * 64;

  { // stage packed-B slice (contiguous) into LDS
    const int n16 = 2*NT*KT*64;
    const i32x4* src = (const i32x4*)(Bp + (size_t)(col0>>4)*KT*64*8);
    i32x4* dst = (i32x4*)smem;
    for (int i=tid; i<n16; i+=512) dst[i] = src[i];
  }
  __syncthreads();

  f32x4 acc[NT];
#pragma unroll
  for (int nt=0; nt<NT; ++nt) acc[nt] = (f32x4){0.f,0.f,0.f,0.f};

  const int rowA = row0 + mw*16 + l15;
#pragma unroll
  for (int kt=0; kt<KT; ++kt){
    bf16x8 a;
    const int k0 = kt*32 + g4*8;
    if constexpr (AF32){
      const float* ap = (const float*)A_ + (size_t)rowA*lda + k0;
      const f32x4 x0 = *(const f32x4*)ap;
      const f32x4 x1 = *(const f32x4*)(ap+4);
#pragma unroll
      for (int j=0;j<4;++j){ a[j] = (short)f2b(x0[j]); a[j+4] = (short)f2b(x1[j]); }
    } else {
      a = *(const bf16x8*)((const u16*)A_ + (size_t)rowA*lda + k0);
    }
#pragma unroll
    for (int nt=0; nt<NT; ++nt){
      const bf16x8 b = *(const bf16x8*)(smem + (size_t)(((nw*NT+nt)*KT + kt)*64 + l)*16);
      acc[nt] = mfma16(a,b,acc[nt]);
    }
  }

  __syncthreads();   // drain ALL A-loads in the block before in-place C-stores

#pragma unroll
  for (int nt=0; nt<NT; ++nt){
    const int col = col0 + (nw*NT+nt)*16 + l15;
    const float bv = bias[col];
#pragma unroll
    for (int i=0;i<4;++i){
      const int row = row0 + mw*16 + 4*g4 + i;
      const float v = acc[nt][i] + bv;
      if constexpr (CB16) ((u16*)C_)[(size_t)row*ldc + col] = f2b(v);
      else ((float*)C_)[(size_t)row*ldc + col] = v;
    }
  }
}

// ---------------------------------------------------------------------------
// Recurrent LSTM chunk: TC steps. 16 WGs x 512 thr (8 waves). WG owns batch
// rows [16*wg,16*wg+16). Wave w owns hidden units [32w,32w+32) => gate cols
// {q*256+32w+[0,32)}, 8 n-tiles. n-tiles 0..5 (i,f,g) in VGPRs; 6..7 (o) in
// LDS (pre-staged frags). h double-buffered in LDS (rows padded to 528B).
// xg_t prefetched directly into the MFMA accumulator. 1 barrier / step.
// ---------------------------------------------------------------------------
__global__ __launch_bounds__(512,2) void lstm_rec(const float* __restrict__ xg,
    const u16* __restrict__ Whhp, const float* h_in, const float* c_in,
    u16* __restrict__ y, float* h_out, float* c_out)
{
  __shared__ char smW[131072];     // o-gate frags: ((w*16+ntl*8+kt)*64+l)*16
  __shared__ char smH[2][8448];    // h bufs: row b at b*528, col jh at 2*jh
  const int tid = threadIdx.x;
  const int w = tid >> 6, l = tid & 63;
  const int l15 = l & 15, g4 = l >> 4;
  const int b0 = (int)blockIdx.x * 16;

  // ---- Whh fragments: reg n-tiles 0..5 (gates i,f,g) ----
  bf16x8 Wr[6][8];
#pragma unroll
  for (int nt=0; nt<6; ++nt){
    const int ntg = ((nt>>1)<<4) + (w<<1) + (nt&1);
#pragma unroll
    for (int kt=0; kt<8; ++kt)
      Wr[nt][kt] = *(const bf16x8*)(Whhp + (((size_t)ntg*8 + kt)*64 + l)*8);
  }
  // ---- o-gate n-tiles (6,7) -> LDS in frag layout ----
#pragma unroll
  for (int ntl=0; ntl<2; ++ntl){
    const int ntg = 48 + (w<<1) + ntl;
#pragma unroll
    for (int kt=0; kt<8; ++kt){
      bf16x8 v = *(const bf16x8*)(Whhp + (((size_t)ntg*8 + kt)*64 + l)*8);
      *(bf16x8*)(smW + (size_t)((w*16 + ntl*8 + kt)*64 + l)*16) = v;
    }
  }

  // ---- init c (regs) and h (LDS buf0, bf16) from h_in/c_in ----
  float c[2][4];
#pragma unroll
  for (int hf=0; hf<2; ++hf)
#pragma unroll
    for (int i=0;i<4;++i){
      const int b  = 4*g4 + i;
      const int jh = 32*w + 16*hf + l15;
      c[hf][i] = c_in[(size_t)(b0+b)*256 + jh];
      *(u16*)(&smH[0][0] + (size_t)b*528 + 2*jh) = f2b(h_in[(size_t)(b0+b)*256 + jh]);
    }

  f32x4 acc[8];
  auto xg_load = [&](int t){
    const size_t rb = ((size_t)t*256 + b0 + 4*g4)*1024 + 32*w + l15;
#pragma unroll
    for (int nt=0; nt<8; ++nt){
      const size_t cb = rb + 256*(nt>>1) + 16*(nt&1);
#pragma unroll
      for (int i=0;i<4;++i) acc[nt][i] = xg[cb + (size_t)i*1024];
    }
  };
  xg_load(0);
  __syncthreads();   // W-LDS + h visible

  for (int t = 0; t < TC; ++t) {
    const char* hrd = &smH[t&1][0];
    char*       hwr = &smH[(t&1)^1][0];

    // gates = xg_t (preloaded in acc) + h_t @ Whh^T
#pragma unroll
    for (int kt=0; kt<8; ++kt){
      const bf16x8 a = *(const bf16x8*)(hrd + (size_t)l15*528 + kt*64 + g4*16);
#pragma unroll
      for (int nt=0; nt<6; ++nt) acc[nt] = mfma16(a, Wr[nt][kt], acc[nt]);
#pragma unroll
      for (int ntl=0; ntl<2; ++ntl){
        const bf16x8 wl = *(const bf16x8*)(smW + (size_t)((w*16 + ntl*8 + kt)*64 + l)*16);
        acc[6+ntl] = mfma16(a, wl, acc[6+ntl]);
      }
    }

    // nonlinearity + state update (lane-local)
#pragma unroll
    for (int hf=0; hf<2; ++hf){
#pragma unroll
      for (int i=0;i<4;++i){
        const float iv = fsig (acc[0+hf][i]);
        const float fv = fsig (acc[2+hf][i]);
        const float gv = ftanh(acc[4+hf][i]);
        const float ov = fsig (acc[6+hf][i]);
        const float cc = fv*c[hf][i] + iv*gv;
        c[hf][i] = cc;
        const float hh = ov*ftanh(cc);
        const int b  = 4*g4 + i;
        const int jh = 32*w + 16*hf + l15;
        const u16 hb = f2b(hh);
        *(u16*)(hwr + (size_t)b*528 + 2*jh) = hb;
        y[((size_t)t*256 + b0 + b)*256 + jh] = hb;
        if (t == TC-1){
          h_out[(size_t)(b0+b)*256 + jh] = hh;
          c_out[(size_t)(b0+b)*256 + jh] = cc;
        }
      }
    }
    if (t < TC-1) xg_load(t+1);   // prefetch next step's xg into acc
    __syncthreads();              // h writes visible before next step
  }
}

// ---------------------------------------------------------------------------
extern "C" void kernel_launch(void* const* d_in, const int* in_sizes, int n_in,
                              void* d_out, int out_size, void* d_ws, size_t ws_size,
                              hipStream_t stream) {
  (void)in_sizes; (void)n_in; (void)out_size; (void)ws_size;
  const float* x    = (const float*)d_in[0];
  const float* h0   = (const float*)d_in[1];
  const float* c0   = (const float*)d_in[2];
  const float* Wih0 = (const float*)d_in[3];
  const float* Whh0 = (const float*)d_in[4];
  const float* bih0 = (const float*)d_in[5];
  const float* bhh0 = (const float*)d_in[6];
  const float* Wih1 = (const float*)d_in[7];
  const float* Whh1 = (const float*)d_in[8];
  const float* bih1 = (const float*)d_in[9];
  const float* bhh1 = (const float*)d_in[10];
  const float* Wfc  = (const float*)d_in[11];
  const float* bfc  = (const float*)d_in[12];
  float* out = (float*)d_out;

  // ---- workspace layout (74.8 MB total) ----
  char* p = (char*)d_ws;
  float* xgc  = (float*)p;            p += (size_t)TC*BB*1024*4;   // 67,108,864
  u16*   y0c  = (u16*)p;              p += (size_t)TC*BB*HH*2;     //  8,388,608
  u16*  whh0p = (u16*)p;              p += 524288;
  u16*  whh1p = (u16*)p;              p += 524288;
  u16*  wih0p = (u16*)p;              p += 262144;
  u16*  wih1p = (u16*)p;              p += 524288;
  u16*  wfcp  = (u16*)p;              p += 65536;
  float* bias0 = (float*)p;           p += 4096;
  float* bias1 = (float*)p;           p += 4096;
  float* hst0 = (float*)p;            p += 262144;
  float* cst0 = (float*)p;            p += 262144;
  float* hst1 = (float*)p;            p += 262144;
  float* cst1 = (float*)p;            p += 262144;

  u16* y1   = (u16*)d_out;            // bf16 y1 aliases out region (67 MB);
  float* hid = out + 16777216;        // FC rewrites rows it reads (barrier'd)
  float* cel = hid + 131072;

  // ---- weight packing + bias sums (every call; deterministic) ----
  pack_b<<<64 ,256,0,stream>>>(Wih0, wih0p, 1024,128);
  pack_b<<<128,256,0,stream>>>(Whh0, whh0p, 1024,256);
  pack_b<<<128,256,0,stream>>>(Wih1, wih1p, 1024,256);
  pack_b<<<128,256,0,stream>>>(Whh1, whh1p, 1024,256);
  pack_b<<<16 ,256,0,stream>>>(Wfc,  wfcp,  128,256);
  bias_sum<<<8,256,0,stream>>>(bih0,bhh0,bias0, bih1,bhh1,bias1);

  // ---- chunked two-layer pipeline ----
  for (int k=0; k<NCH; ++k){
    const bool first = (k==0), last = (k==NCH-1);
    gemm_xg<4,8,true ,false><<<dim3(4,TC*BB/64),512,0,stream>>>(
        x + (size_t)k*TC*BB*VV, wih0p, bias0, xgc, VV, 1024);
    lstm_rec<<<16,512,0,stream>>>(xgc, whh0p,
        first ? h0 : hst0, first ? c0 : cst0, y0c,
        last ? hid : hst0, last ? cel : cst0);
    gemm_xg<8,8,false,false><<<dim3(4,TC*BB/64),512,0,stream>>>(
        y0c, wih1p, bias1, xgc, HH, 1024);
    lstm_rec<<<16,512,0,stream>>>(xgc, whh1p,
        first ? (h0+65536) : hst1, first ? (c0+65536) : cst1,
        y1 + (size_t)k*TC*BB*HH,
        last ? (hid+65536) : hst1, last ? (cel+65536) : cst1);
  }

  // ---- FC: out = y1 @ Wfc^T + bfc (reads y1 bf16 from d_out, overwrites
  // the same rows with f32; safe via pre-epilogue barrier in gemm_xg) ----
  gemm_xg<8,4,false,false><<<dim3(1,TT*BB/64),512,0,stream>>>(
      y1, wfcp, bfc, out, HH, VV);
}

// Round 4
// 2182.789 us; speedup vs baseline: 1.4833x; 1.4833x over previous
//
#include <hip/hip_runtime.h>
#include <hip/hip_bf16.h>

#define DI __device__ __forceinline__

typedef short bf16x8 __attribute__((ext_vector_type(8)));
typedef float f32x4 __attribute__((ext_vector_type(4)));
typedef int   i32x4 __attribute__((ext_vector_type(4)));
typedef unsigned short u16;

constexpr int TT = 512, BB = 256, HH = 256, VV = 128;
constexpr int TC = 32, NCH = TT / TC;   // timestep chunk per rec dispatch
static_assert((TC & 1) == 0, "final h parity assumes even TC");

DI u16 f2b(float f){ __hip_bfloat16 h = __float2bfloat16(f); u16 r; __builtin_memcpy(&r,&h,2); return r; }
DI float b2f(u16 v){ unsigned u = ((unsigned)v)<<16; float f; __builtin_memcpy(&f,&u,4); return f; }
DI float fsig(float x){ return __builtin_amdgcn_rcpf(1.0f + __builtin_amdgcn_exp2f(-1.4426950408889634f*x)); }
DI float ftanh(float x){ return 1.0f - 2.0f*__builtin_amdgcn_rcpf(1.0f + __builtin_amdgcn_exp2f(2.8853900817779268f*x)); }
DI f32x4 mfma16(bf16x8 a, bf16x8 b, f32x4 c){ return __builtin_amdgcn_mfma_f32_16x16x32_bf16(a,b,c,0,0,0); }

// ---------------------------------------------------------------------------
// pack W [N][K] f32 -> B-fragment layout: frag(ntg,kt,lane)[j] =
//   bf16( W[ntg*16 + (lane&15)][kt*32 + (lane>>4)*8 + j] ), linear at tid*8.
// ---------------------------------------------------------------------------
__global__ void pack_b(const float* __restrict__ W, u16* __restrict__ o, int N, int K){
  const int tid = blockIdx.x*256 + threadIdx.x;
  const int KT = K >> 5;
  const int total = (N>>4)*KT*64;
  if (tid >= total) return;
  const int lane = tid & 63;
  const int rest = tid >> 6;
  const int kt  = rest % KT;
  const int ntg = rest / KT;
  const int n  = (ntg<<4) + (lane&15);
  const int k0 = (kt<<5) + ((lane>>4)<<3);
  const float* s = W + (size_t)n*K + k0;
  bf16x8 pv;
#pragma unroll
  for (int j=0;j<8;++j) pv[j] = (short)f2b(s[j]);
  *(bf16x8*)(o + (size_t)tid*8) = pv;
}

__global__ void bias_sum(const float* a0,const float* b0,float* o0,
                         const float* a1,const float* b1,float* o1){
  int i = blockIdx.x*256 + threadIdx.x;
  if (i < 1024) o0[i] = a0[i] + b0[i];
  else if (i < 2048) { int j=i-1024; o1[j] = a1[j] + b1[j]; }
}

// ---------------------------------------------------------------------------
// GEMM body producing PERMUTED bf16 xg for the rec kernel.
// NT==8 assumed (256 cols/block, grid.x = 4 = gate quadrant q).
// Permuted layout (bf16 elems): idx = (((t*16+bg)*8 + w)*64 + l)*32 + nt*4 + i
// where for output element (row,col): t=row>>8, bg=(row&255)>>4, lane-in-rec
// l=(g4<<4)|l15 (== this gemm lane's own l), w=((nw*8+nt)>>1)&7,
// nt_rec=2*q+((nw*8+nt)&1), i = acc reg index (row = ... + 4*g4 + i).
// Verified example: (t=0,B=17,col=296) -> idx 18697 on both producer/consumer.
// ---------------------------------------------------------------------------
template<int KT, bool AF32>
DI void gemm_body(char* smem, const void* A_, const u16* __restrict__ Bp,
                  const float* __restrict__ bias, u16* __restrict__ xgp,
                  int lda, int bx, int by)
{
  constexpr int NT = 8;
  const int tid = threadIdx.x;
  const int l = tid & 63, w = tid >> 6;
  const int l15 = l & 15, g4 = l >> 4;
  const int mw = w >> 1, nw = w & 1;
  const int col0 = bx * 256;
  const int row0 = by * 64;

  { // stage packed-B slice (contiguous) into LDS
    const int n16 = 2*NT*KT*64;
    const i32x4* src = (const i32x4*)(Bp + (size_t)(col0>>4)*KT*64*8);
    i32x4* dst = (i32x4*)smem;
    for (int i=tid; i<n16; i+=512) dst[i] = src[i];
  }
  __syncthreads();

  f32x4 acc[NT];
#pragma unroll
  for (int nt=0; nt<NT; ++nt) acc[nt] = (f32x4){0.f,0.f,0.f,0.f};

  const int rowA = row0 + mw*16 + l15;
#pragma unroll
  for (int kt=0; kt<KT; ++kt){
    bf16x8 a;
    const int k0 = kt*32 + g4*8;
    if constexpr (AF32){
      const float* ap = (const float*)A_ + (size_t)rowA*lda + k0;
      const f32x4 x0 = *(const f32x4*)ap;
      const f32x4 x1 = *(const f32x4*)(ap+4);
#pragma unroll
      for (int j=0;j<4;++j){ a[j] = (short)f2b(x0[j]); a[j+4] = (short)f2b(x1[j]); }
    } else {
      a = *(const bf16x8*)((const u16*)A_ + (size_t)rowA*lda + k0);
    }
#pragma unroll
    for (int nt=0; nt<NT; ++nt){
      const bf16x8 b = *(const bf16x8*)(smem + (size_t)(((nw*NT+nt)*KT + kt)*64 + l)*16);
      acc[nt] = mfma16(a,b,acc[nt]);
    }
  }

  // permuted epilogue
  const int t   = row0 >> 8;          // rows [row0,row0+64) never cross 256
  const int bgb = (row0 & 255) >> 4;  // + mw -> bg
#pragma unroll
  for (int nt=0; nt<NT; ++nt){
    const int nn  = nw*8 + nt;
    const int wr  = nn >> 1;
    const int ntr = 2*bx + (nn & 1);
    const float bv = bias[col0 + nn*16 + l15];
    const size_t base = (((size_t)(t*16 + bgb + mw)*8 + wr)*64 + l)*32 + ntr*4;
#pragma unroll
    for (int i=0;i<4;++i)
      xgp[base + i] = f2b(acc[nt][i] + bv);
  }
}

template<int KT, bool AF32>
__global__ __launch_bounds__(512,2) void gemm_perm(const void* A, const u16* Bp,
    const float* bias, u16* xgp, int lda){
  __shared__ char smem[2*8*KT*64*16];
  gemm_body<KT,AF32>(smem, A, Bp, bias, xgp, lda, blockIdx.x, blockIdx.y);
}

// fused: z=0 -> layer0 gemm (x f32, KT=4), z=1 -> layer1 gemm (y0 bf16, KT=8)
__global__ __launch_bounds__(512,2) void gemm_dual(
    const float* x0, const u16* wih0, const float* bias0, u16* xg0,
    const u16*  y0, const u16* wih1, const float* bias1, u16* xg1){
  __shared__ char smem[131072];
  if (blockIdx.z == 0) gemm_body<4,true >(smem, x0, wih0, bias0, xg0, 128, blockIdx.x, blockIdx.y);
  else                 gemm_body<8,false>(smem, y0, wih1, bias1, xg1, 256, blockIdx.x, blockIdx.y);
}

// ---------------------------------------------------------------------------
// Classic-epilogue GEMM for the final FC only (f32 row-major out, in-place
// over bf16 A => pre-epilogue barrier REQUIRED).
// ---------------------------------------------------------------------------
template<int KT, int NT>
__global__ __launch_bounds__(512,2) void gemm_fc(const u16* __restrict__ A_,
    const u16* __restrict__ Bp, const float* __restrict__ bias,
    float* C_, int lda, int ldc)
{
  __shared__ char smem[2*NT*KT*64*16];
  const int tid = threadIdx.x;
  const int l = tid & 63, w = tid >> 6;
  const int l15 = l & 15, g4 = l >> 4;
  const int mw = w >> 1, nw = w & 1;
  const int col0 = blockIdx.x * (NT*32);
  const int row0 = blockIdx.y * 64;

  {
    const int n16 = 2*NT*KT*64;
    const i32x4* src = (const i32x4*)(Bp + (size_t)(col0>>4)*KT*64*8);
    i32x4* dst = (i32x4*)smem;
    for (int i=tid; i<n16; i+=512) dst[i] = src[i];
  }
  __syncthreads();

  f32x4 acc[NT];
#pragma unroll
  for (int nt=0; nt<NT; ++nt) acc[nt] = (f32x4){0.f,0.f,0.f,0.f};

  const int rowA = row0 + mw*16 + l15;
#pragma unroll
  for (int kt=0; kt<KT; ++kt){
    const bf16x8 a = *(const bf16x8*)(A_ + (size_t)rowA*lda + kt*32 + g4*8);
#pragma unroll
    for (int nt=0; nt<NT; ++nt){
      const bf16x8 b = *(const bf16x8*)(smem + (size_t)(((nw*NT+nt)*KT + kt)*64 + l)*16);
      acc[nt] = mfma16(a,b,acc[nt]);
    }
  }

  __syncthreads();   // drain all A-loads in block before in-place C-stores

#pragma unroll
  for (int nt=0; nt<NT; ++nt){
    const int col = col0 + (nw*NT+nt)*16 + l15;
    const float bv = bias[col];
#pragma unroll
    for (int i=0;i<4;++i)
      C_[(size_t)(row0 + mw*16 + 4*g4 + i)*ldc + col] = acc[nt][i] + bv;
  }
}

// ---------------------------------------------------------------------------
// Fused dual-layer recurrent chunk: TC steps. Blocks 0..15 run param-set A,
// blocks 16..31 set B (independent layers/chunks). Per block: batch rows
// [16*bg,16*bg+16). Wave w owns hidden units [32w,32w+32) -> 8 gate n-tiles;
// tiles 0..5 (i,f,g) in VGPRs, 6..7 (o) in LDS. h double-buffered in LDS.
// xg read bf16 from the permuted layout via a stepping pointer, staged one
// step ahead in regs (xsv), consumed as the kt=0 MFMA C-input.
// ---------------------------------------------------------------------------
__global__ __launch_bounds__(512,2) void lstm_rec2(
    const u16* __restrict__ xgA, const u16* __restrict__ whA,
    const float* hinA, const float* cinA, u16* yA, float* houtA, float* coutA,
    const u16* __restrict__ xgB, const u16* __restrict__ whB,
    const float* hinB, const float* cinB, u16* yB, float* houtB, float* coutB)
{
  __shared__ char smW[131072];     // o-gate frags: ((w*16+ntl*8+kt)*64+l)*16
  __shared__ char smH[2][8448];    // h bufs: row b at b*528, col jh at 2*jh
  const int tid = threadIdx.x;
  const int w = tid >> 6, l = tid & 63;
  const int l15 = l & 15, g4 = l >> 4;
  const int lay = (int)blockIdx.x >> 4;
  const int bg  = (int)blockIdx.x & 15;
  const int b0  = bg * 16;

  const u16* xg   = lay ? xgB : xgA;
  const u16* Whhp = lay ? whB : whA;
  const float* h_in = lay ? hinB : hinA;
  const float* c_in = lay ? cinB : cinA;
  u16* y = lay ? yB : yA;

  // stepping pointers
  const u16* xp = xg + ((size_t)(bg*8 + w)*64 + l)*32;          // +262144/step
  u16* yp = y + (size_t)(b0 + 4*g4)*256 + 32*w + l15;           // +65536/step

  // prefetch xg(t=0): 4 x dwordx4 per lane (32 bf16, lane-contiguous)
  bf16x8 xsv[4];
#pragma unroll
  for (int k2=0;k2<4;++k2) xsv[k2] = *(const bf16x8*)(xp + k2*8);

  // Whh fragments: reg n-tiles 0..5 (gates i,f,g)
  bf16x8 Wr[6][8];
#pragma unroll
  for (int nt=0; nt<6; ++nt){
    const int ntg = ((nt>>1)<<4) + (w<<1) + (nt&1);
#pragma unroll
    for (int kt=0; kt<8; ++kt)
      Wr[nt][kt] = *(const bf16x8*)(Whhp + (((size_t)ntg*8 + kt)*64 + l)*8);
  }
  // o-gate n-tiles (6,7) -> LDS in frag layout
#pragma unroll
  for (int ntl=0; ntl<2; ++ntl){
    const int ntg = 48 + (w<<1) + ntl;
#pragma unroll
    for (int kt=0; kt<8; ++kt){
      bf16x8 v = *(const bf16x8*)(Whhp + (((size_t)ntg*8 + kt)*64 + l)*8);
      *(bf16x8*)(smW + (size_t)((w*16 + ntl*8 + kt)*64 + l)*16) = v;
    }
  }

  // init c (regs) and h (LDS buf0, bf16)
  float c[2][4];
#pragma unroll
  for (int hf=0; hf<2; ++hf)
#pragma unroll
    for (int i=0;i<4;++i){
      const int b  = 4*g4 + i;
      const int jh = 32*w + 16*hf + l15;
      c[hf][i] = c_in[(size_t)(b0+b)*256 + jh];
      *(u16*)(&smH[0][0] + (size_t)b*528 + 2*jh) = f2b(h_in[(size_t)(b0+b)*256 + jh]);
    }
  __syncthreads();   // W-LDS + h visible

  for (int t = 0; t < TC; ++t) {
    const char* hrd = &smH[t&1][0];
    char*       hwr = &smH[(t&1)^1][0];

    // kt=0: C-input = staged xg(t); then immediately restage xg(t+1)
    const bf16x8 a0 = *(const bf16x8*)(hrd + (size_t)l15*528 + g4*16);
    f32x4 acc[8];
#pragma unroll
    for (int nt=0; nt<6; ++nt){
      f32x4 x0; 
#pragma unroll
      for (int i=0;i<4;++i) x0[i] = b2f((u16)xsv[nt>>1][(nt&1)*4+i]);
      acc[nt] = mfma16(a0, Wr[nt][0], x0);
    }
#pragma unroll
    for (int ntl=0; ntl<2; ++ntl){
      const int nt = 6+ntl;
      f32x4 x0;
#pragma unroll
      for (int i=0;i<4;++i) x0[i] = b2f((u16)xsv[nt>>1][(nt&1)*4+i]);
      const bf16x8 wl = *(const bf16x8*)(smW + (size_t)((w*16 + ntl*8)*64 + l)*16);
      acc[nt] = mfma16(a0, wl, x0);
    }
    xp += 262144;                       // next step's slab (1MB-slack padded)
#pragma unroll
    for (int k2=0;k2<4;++k2) xsv[k2] = *(const bf16x8*)(xp + k2*8);

    // kt=1..7
#pragma unroll
    for (int kt=1; kt<8; ++kt){
      const bf16x8 a = *(const bf16x8*)(hrd + (size_t)l15*528 + kt*64 + g4*16);
#pragma unroll
      for (int nt=0; nt<6; ++nt) acc[nt] = mfma16(a, Wr[nt][kt], acc[nt]);
#pragma unroll
      for (int ntl=0; ntl<2; ++ntl){
        const bf16x8 wl = *(const bf16x8*)(smW + (size_t)((w*16 + ntl*8 + kt)*64 + l)*16);
        acc[6+ntl] = mfma16(a, wl, acc[6+ntl]);
      }
    }

    // nonlinearity + state update (lane-local)
#pragma unroll
    for (int hf=0; hf<2; ++hf){
#pragma unroll
      for (int i=0;i<4;++i){
        const float iv = fsig (acc[0+hf][i]);
        const float fv = fsig (acc[2+hf][i]);
        const float gv = ftanh(acc[4+hf][i]);
        const float ov = fsig (acc[6+hf][i]);
        const float cc = fv*c[hf][i] + iv*gv;
        c[hf][i] = cc;
        const float hh = ov*ftanh(cc);
        const u16 hb = f2b(hh);
        *(u16*)(hwr + (size_t)(4*g4+i)*528 + 2*(32*w + 16*hf + l15)) = hb;
        yp[(size_t)i*256 + hf*16] = hb;
      }
    }
    yp += 65536;
    __syncthreads();              // h writes visible before next step
  }

  // final state write-back (TC even -> last h in smH[0]); own elements only.
  float* hout = lay ? houtB : houtA;
  float* cout = lay ? coutB : coutA;
#pragma unroll
  for (int hf=0; hf<2; ++hf)
#pragma unroll
    for (int i=0;i<4;++i){
      const int b  = 4*g4 + i;
      const int jh = 32*w + 16*hf + l15;
      hout[(size_t)(b0+b)*256 + jh] = b2f(*(u16*)(&smH[0][0] + (size_t)b*528 + 2*jh));
      cout[(size_t)(b0+b)*256 + jh] = c[hf][i];
    }
}

// ---------------------------------------------------------------------------
extern "C" void kernel_launch(void* const* d_in, const int* in_sizes, int n_in,
                              void* d_out, int out_size, void* d_ws, size_t ws_size,
                              hipStream_t stream) {
  (void)in_sizes; (void)n_in; (void)out_size; (void)ws_size;
  const float* x    = (const float*)d_in[0];
  const float* h0   = (const float*)d_in[1];
  const float* c0   = (const float*)d_in[2];
  const float* Wih0 = (const float*)d_in[3];
  const float* Whh0 = (const float*)d_in[4];
  const float* bih0 = (const float*)d_in[5];
  const float* bhh0 = (const float*)d_in[6];
  const float* Wih1 = (const float*)d_in[7];
  const float* Whh1 = (const float*)d_in[8];
  const float* bih1 = (const float*)d_in[9];
  const float* bhh1 = (const float*)d_in[10];
  const float* Wfc  = (const float*)d_in[11];
  const float* bfc  = (const float*)d_in[12];
  float* out = (float*)d_out;

  // ---- workspace layout (~42 MB) ----
  constexpr size_t XGC = (size_t)TC*BB*1024;      // bf16 elems per xg chunk
  char* p = (char*)d_ws;
  u16* xgc0 = (u16*)p;   p += XGC*2 + 1048576;    // +1MB prefetch slack
  u16* xgc1 = (u16*)p;   p += XGC*2 + 1048576;
  u16* y0c  = (u16*)p;   p += (size_t)TC*BB*HH*2;
  u16* whh0p = (u16*)p;  p += 524288;
  u16* whh1p = (u16*)p;  p += 524288;
  u16* wih0p = (u16*)p;  p += 262144;
  u16* wih1p = (u16*)p;  p += 524288;
  u16* wfcp  = (u16*)p;  p += 65536;
  float* bias0 = (float*)p; p += 4096;
  float* bias1 = (float*)p; p += 4096;
  float* hst0 = (float*)p;  p += 262144;
  float* cst0 = (float*)p;  p += 262144;
  float* hst1 = (float*)p;  p += 262144;
  float* cst1 = (float*)p;  p += 262144;

  u16* y1    = (u16*)d_out;          // bf16 y1 aliases out region;
  float* hid = out + 16777216;       // FC rewrites rows it reads (barrier'd)
  float* cel = hid + 131072;

  // ---- weight packing + bias sums (every call; deterministic) ----
  pack_b<<<64 ,256,0,stream>>>(Wih0, wih0p, 1024,128);
  pack_b<<<128,256,0,stream>>>(Whh0, whh0p, 1024,256);
  pack_b<<<128,256,0,stream>>>(Wih1, wih1p, 1024,256);
  pack_b<<<128,256,0,stream>>>(Whh1, whh1p, 1024,256);
  pack_b<<<16 ,256,0,stream>>>(Wfc,  wfcp,  128,256);
  bias_sum<<<8,256,0,stream>>>(bih0,bhh0,bias0, bih1,bhh1,bias1);

  constexpr int GY = TC*BB/64;   // 128 row-blocks per chunk

  // ---- software-pipelined two-layer schedule ----
  // g0(0); rec0(0); then per k: [g0(k+1) || g1(k)] ; [rec0(k+1) || rec1(k)]
  gemm_perm<4,true><<<dim3(4,GY),512,0,stream>>>(x, wih0p, bias0, xgc0, 128);
  lstm_rec2<<<16,512,0,stream>>>(xgc0, whh0p, h0, c0, y0c, hst0, cst0,
                                 xgc0, whh0p, h0, c0, y0c, hst0, cst0);
  for (int k=0; k<NCH-1; ++k){
    gemm_dual<<<dim3(4,GY,2),512,0,stream>>>(
        x + (size_t)(k+1)*TC*BB*VV, wih0p, bias0, xgc0,
        y0c, wih1p, bias1, xgc1);
    lstm_rec2<<<32,512,0,stream>>>(
        xgc0, whh0p, hst0, cst0, y0c,
        (k+1==NCH-1) ? hid : hst0, (k+1==NCH-1) ? cel : cst0,
        xgc1, whh1p,
        (k==0) ? (h0+65536) : hst1, (k==0) ? (c0+65536) : cst1,
        y1 + (size_t)k*TC*BB*HH, hst1, cst1);
  }
  // final layer-1 chunk
  gemm_perm<8,false><<<dim3(4,GY),512,0,stream>>>(y0c, wih1p, bias1, xgc1, 256);
  lstm_rec2<<<16,512,0,stream>>>(
      xgc1, whh1p, hst1, cst1, y1 + (size_t)(NCH-1)*TC*BB*HH, hid+65536, cel+65536,
      xgc1, whh1p, hst1, cst1, y1 + (size_t)(NCH-1)*TC*BB*HH, hid+65536, cel+65536);

  // ---- FC: out = y1 @ Wfc^T + bfc (in-place over bf16 y1; barrier'd) ----
  gemm_fc<8,4><<<dim3(1,TT*BB/64),512,0,stream>>>(y1, wfcp, bfc, out, 256, 128);
}